// Round 8
// baseline (54.802 us; speedup 1.0000x reference)
//
#include <hip/hip_runtime.h>
#include <math.h>

#define EPS 1e-8f
constexpr int N = 8192;
constexpr int ROWS_PER_BLOCK = 8;
constexpr int COLS_PER_BLOCK = 2048;   // 256 threads * 8 floats (2x float4)
constexpr float LPOS = 0.7310585786300049f;  // sigmoid(+1)
constexpr float LNEG = 0.2689414213699951f;  // sigmoid(-1)

// ---------------------------------------------------------------------------
// Fused match kernel: one wave per row. Lane L owns h in {L,L+64,L+128,L+192};
// computes p1[h],p2[h] redundantly (Wp/bp L1-resident) + its row's props,
// wave-reduces 5 dots: |props|^2, props.p1, props.p2, |p1|^2, |p2|^2.
// Writes: m2[row], subj[row], rowpack[row] = {m1, obj, EPS/|obj|, 0}.
// ---------------------------------------------------------------------------
__global__ __launch_bounds__(256) void match_kernel(
    const float* __restrict__ pat1, const float* __restrict__ pat2,
    const float* __restrict__ Wp, const float* __restrict__ bp,
    const float* __restrict__ wm, const float* __restrict__ Wq,
    const float* __restrict__ bq,
    float4* __restrict__ rowpack, float* __restrict__ m2,
    float* __restrict__ subj) {
  const int row = (blockIdx.x * blockDim.x + threadIdx.x) >> 6;
  const int lane = threadIdx.x & 63;
  const float a0 = pat1[0], a1 = pat1[1], a2 = pat1[2];
  const float b0 = pat2[0], b1 = pat2[1], b2 = pat2[2];
  const float x0 = wm[row * 3 + 0];
  const float x1 = wm[row * 3 + 1];
  const float x2 = wm[row * 3 + 2];
  float s0 = 0.f, s1 = 0.f, s2 = 0.f, n1 = 0.f, n2 = 0.f;
#pragma unroll
  for (int k = 0; k < 4; ++k) {
    const int h = lane + k * 64;
    const float wp0 = Wp[h * 3 + 0], wp1 = Wp[h * 3 + 1], wp2 = Wp[h * 3 + 2];
    const float bph = bp[h];
    const float v1 = fmaf(wp0, a0, fmaf(wp1, a1, fmaf(wp2, a2, bph)));
    const float v2 = fmaf(wp0, b0, fmaf(wp1, b1, fmaf(wp2, b2, bph)));
    const float v  = fmaf(Wq[h * 3 + 0], x0,
                     fmaf(Wq[h * 3 + 1], x1,
                     fmaf(Wq[h * 3 + 2], x2, bq[h])));
    s0 = fmaf(v, v, s0);
    s1 = fmaf(v, v1, s1);
    s2 = fmaf(v, v2, s2);
    n1 = fmaf(v1, v1, n1);
    n2 = fmaf(v2, v2, n2);
  }
#pragma unroll
  for (int off = 32; off > 0; off >>= 1) {
    s0 += __shfl_xor(s0, off, 64);
    s1 += __shfl_xor(s1, off, 64);
    s2 += __shfl_xor(s2, off, 64);
    n1 += __shfl_xor(n1, off, 64);
    n2 += __shfl_xor(n2, off, 64);
  }
  if (lane == 0) {
    const float pn = sqrtf(s0);
    const float d1 = fmaxf(pn * sqrtf(n1), EPS);
    const float d2 = fmaxf(pn * sqrtf(n2), EPS);
    const float mm1 = 1.f / (1.f + __expf(-(s1 / d1)));
    const float mm2 = 1.f / (1.f + __expf(-(s2 / d2)));
    m2[row]   = mm2;
    subj[row] = x0;
    float4 rp;
    rp.x = mm1;                 // m1[i]
    rp.y = x2;                  // obj[i]
    rp.z = EPS / fabsf(x2);     // rare threshold: |subj_j| < thr <=> |t| < EPS
    rp.w = 0.f;
    rowpack[row] = rp;
  }
}

// ---------------------------------------------------------------------------
// Outer kernel. Each thread owns 8 columns (2x float4, 32 B/lane) across 8
// rows: 16 stores per wave-life vs 8 before — amortizes the end-of-wave
// vmcnt drain. Fast path: link = sigmoid(+/-1) const folded into per-column
// qp/qm, 1 select + 1 mul per element. Rare eps path exact. diag zeroed.
// Plain float4 stores (nt measured slower: bypasses L2/LLC write path).
// Persistent/register-prefetch variant measured slower (VGPR-occupancy).
// ---------------------------------------------------------------------------
__device__ __forceinline__ float exact_elem(float a, float oi, float m2c,
                                            float sjc) {
  const float t = oi * sjc;
  const float z = t / fmaxf(fabsf(t), EPS);
  return a * m2c * (1.f / (1.f + __expf(-z)));
}

__global__ __launch_bounds__(256) void outer_kernel(
    const float4* __restrict__ rowpack, const float* __restrict__ m2,
    const float* __restrict__ subj, float* __restrict__ out) {
  const int jBase = blockIdx.x * COLS_PER_BLOCK + threadIdx.x * 8;
  const int iBase = blockIdx.y * ROWS_PER_BLOCK;
  const float4 m2a = *reinterpret_cast<const float4*>(m2 + jBase);
  const float4 m2b = *reinterpret_cast<const float4*>(m2 + jBase + 4);
  const float4 sja = *reinterpret_cast<const float4*>(subj + jBase);
  const float4 sjb = *reinterpret_cast<const float4*>(subj + jBase + 4);
  float4 qpa, qma, qpb, qmb, asa, asb;
  qpa.x = m2a.x * (sja.x > 0.f ? LPOS : LNEG);
  qpa.y = m2a.y * (sja.y > 0.f ? LPOS : LNEG);
  qpa.z = m2a.z * (sja.z > 0.f ? LPOS : LNEG);
  qpa.w = m2a.w * (sja.w > 0.f ? LPOS : LNEG);
  qma.x = m2a.x * (sja.x > 0.f ? LNEG : LPOS);
  qma.y = m2a.y * (sja.y > 0.f ? LNEG : LPOS);
  qma.z = m2a.z * (sja.z > 0.f ? LNEG : LPOS);
  qma.w = m2a.w * (sja.w > 0.f ? LNEG : LPOS);
  qpb.x = m2b.x * (sjb.x > 0.f ? LPOS : LNEG);
  qpb.y = m2b.y * (sjb.y > 0.f ? LPOS : LNEG);
  qpb.z = m2b.z * (sjb.z > 0.f ? LPOS : LNEG);
  qpb.w = m2b.w * (sjb.w > 0.f ? LPOS : LNEG);
  qmb.x = m2b.x * (sjb.x > 0.f ? LNEG : LPOS);
  qmb.y = m2b.y * (sjb.y > 0.f ? LNEG : LPOS);
  qmb.z = m2b.z * (sjb.z > 0.f ? LNEG : LPOS);
  qmb.w = m2b.w * (sjb.w > 0.f ? LNEG : LPOS);
  asa.x = fabsf(sja.x); asa.y = fabsf(sja.y);
  asa.z = fabsf(sja.z); asa.w = fabsf(sja.w);
  asb.x = fabsf(sjb.x); asb.y = fabsf(sjb.y);
  asb.z = fabsf(sjb.z); asb.w = fabsf(sjb.w);
  const float minasj = fminf(
      fminf(fminf(asa.x, asa.y), fminf(asa.z, asa.w)),
      fminf(fminf(asb.x, asb.y), fminf(asb.z, asb.w)));
  const bool diagTile = (iBase * (N / COLS_PER_BLOCK) / ROWS_PER_BLOCK /
                         (N / COLS_PER_BLOCK)) >= 0 &&
                        (iBase / COLS_PER_BLOCK) == (int)blockIdx.x;
#pragma unroll
  for (int r = 0; r < ROWS_PER_BLOCK; ++r) {
    const int i = iBase + r;
    const float4 rp = rowpack[i];   // block-uniform address -> scalar load
    const float a = rp.x, oi = rp.y, thr = rp.z;
    const bool neg = oi < 0.f;
    float4 oA, oB;
    oA.x = a * (neg ? qma.x : qpa.x);
    oA.y = a * (neg ? qma.y : qpa.y);
    oA.z = a * (neg ? qma.z : qpa.z);
    oA.w = a * (neg ? qma.w : qpa.w);
    oB.x = a * (neg ? qmb.x : qpb.x);
    oB.y = a * (neg ? qmb.y : qpb.y);
    oB.z = a * (neg ? qmb.z : qpb.z);
    oB.w = a * (neg ? qmb.w : qpb.w);
    if (__builtin_expect(__any(minasj < thr), 0)) {
      if (asa.x < thr) oA.x = exact_elem(a, oi, m2a.x, sja.x);
      if (asa.y < thr) oA.y = exact_elem(a, oi, m2a.y, sja.y);
      if (asa.z < thr) oA.z = exact_elem(a, oi, m2a.z, sja.z);
      if (asa.w < thr) oA.w = exact_elem(a, oi, m2a.w, sja.w);
      if (asb.x < thr) oB.x = exact_elem(a, oi, m2b.x, sjb.x);
      if (asb.y < thr) oB.y = exact_elem(a, oi, m2b.y, sjb.y);
      if (asb.z < thr) oB.z = exact_elem(a, oi, m2b.z, sjb.z);
      if (asb.w < thr) oB.w = exact_elem(a, oi, m2b.w, sjb.w);
    }
    if (diagTile) {
      if (jBase + 0 == i) oA.x = 0.f;
      if (jBase + 1 == i) oA.y = 0.f;
      if (jBase + 2 == i) oA.z = 0.f;
      if (jBase + 3 == i) oA.w = 0.f;
      if (jBase + 4 == i) oB.x = 0.f;
      if (jBase + 5 == i) oB.y = 0.f;
      if (jBase + 6 == i) oB.z = 0.f;
      if (jBase + 7 == i) oB.w = 0.f;
    }
    float* outp = out + (size_t)i * N + jBase;
    *reinterpret_cast<float4*>(outp) = oA;
    *reinterpret_cast<float4*>(outp + 4) = oB;
  }
}

// ---------------------------------------------------------------------------
extern "C" void kernel_launch(void* const* d_in, const int* in_sizes, int n_in,
                              void* d_out, int out_size, void* d_ws,
                              size_t ws_size, hipStream_t stream) {
  const float* pat1 = (const float*)d_in[0];
  const float* pat2 = (const float*)d_in[1];
  const float* wm   = (const float*)d_in[2];
  const float* Wp   = (const float*)d_in[3];
  const float* bp   = (const float*)d_in[4];
  const float* Wq   = (const float*)d_in[5];
  const float* bq   = (const float*)d_in[6];
  float* out = (float*)d_out;

  // ws layout: rowpack (N float4), m2 (N floats), subj (N floats)
  float4* rowpack = (float4*)d_ws;
  float* m2   = (float*)(rowpack + N);
  float* subj = m2 + N;

  match_kernel<<<N / 4, 256, 0, stream>>>(pat1, pat2, Wp, bp, wm, Wq, bq,
                                          rowpack, m2, subj);
  dim3 grid(N / COLS_PER_BLOCK, N / ROWS_PER_BLOCK);
  outer_kernel<<<grid, 256, 0, stream>>>(rowpack, m2, subj, out);
}

// Round 9
// 51.105 us; speedup vs baseline: 1.0723x; 1.0723x over previous
//
#include <hip/hip_runtime.h>
#include <math.h>

#define EPS 1e-8f
constexpr int N = 8192;
constexpr float LPOS = 0.7310585786300049f;  // sigmoid(+1)
constexpr float LNEG = 0.2689414213699951f;  // sigmoid(-1)

// ---------------------------------------------------------------------------
// Fused match kernel: one wave per row. Lane L owns h in {L,L+64,L+128,L+192};
// computes p1[h],p2[h] redundantly (Wp/bp L1-resident) + its row's props,
// wave-reduces 5 dots: |props|^2, props.p1, props.p2, |p1|^2, |p2|^2.
// Writes: m2[row], subj[row], rowpack[row] = {m1, obj, EPS/|obj|, 0}.
// ---------------------------------------------------------------------------
__global__ __launch_bounds__(256) void match_kernel(
    const float* __restrict__ pat1, const float* __restrict__ pat2,
    const float* __restrict__ Wp, const float* __restrict__ bp,
    const float* __restrict__ wm, const float* __restrict__ Wq,
    const float* __restrict__ bq,
    float4* __restrict__ rowpack, float* __restrict__ m2,
    float* __restrict__ subj) {
  const int row = (blockIdx.x * blockDim.x + threadIdx.x) >> 6;
  const int lane = threadIdx.x & 63;
  const float a0 = pat1[0], a1 = pat1[1], a2 = pat1[2];
  const float b0 = pat2[0], b1 = pat2[1], b2 = pat2[2];
  const float x0 = wm[row * 3 + 0];
  const float x1 = wm[row * 3 + 1];
  const float x2 = wm[row * 3 + 2];
  float s0 = 0.f, s1 = 0.f, s2 = 0.f, n1 = 0.f, n2 = 0.f;
#pragma unroll
  for (int k = 0; k < 4; ++k) {
    const int h = lane + k * 64;
    const float wp0 = Wp[h * 3 + 0], wp1 = Wp[h * 3 + 1], wp2 = Wp[h * 3 + 2];
    const float bph = bp[h];
    const float v1 = fmaf(wp0, a0, fmaf(wp1, a1, fmaf(wp2, a2, bph)));
    const float v2 = fmaf(wp0, b0, fmaf(wp1, b1, fmaf(wp2, b2, bph)));
    const float v  = fmaf(Wq[h * 3 + 0], x0,
                     fmaf(Wq[h * 3 + 1], x1,
                     fmaf(Wq[h * 3 + 2], x2, bq[h])));
    s0 = fmaf(v, v, s0);
    s1 = fmaf(v, v1, s1);
    s2 = fmaf(v, v2, s2);
    n1 = fmaf(v1, v1, n1);
    n2 = fmaf(v2, v2, n2);
  }
#pragma unroll
  for (int off = 32; off > 0; off >>= 1) {
    s0 += __shfl_xor(s0, off, 64);
    s1 += __shfl_xor(s1, off, 64);
    s2 += __shfl_xor(s2, off, 64);
    n1 += __shfl_xor(n1, off, 64);
    n2 += __shfl_xor(n2, off, 64);
  }
  if (lane == 0) {
    const float pn = sqrtf(s0);
    const float d1 = fmaxf(pn * sqrtf(n1), EPS);
    const float d2 = fmaxf(pn * sqrtf(n2), EPS);
    const float mm1 = 1.f / (1.f + __expf(-(s1 / d1)));
    const float mm2 = 1.f / (1.f + __expf(-(s2 / d2)));
    m2[row]   = mm2;
    subj[row] = x0;
    float4 rp;
    rp.x = mm1;                 // m1[i]
    rp.y = x2;                  // obj[i]
    rp.z = EPS / fabsf(x2);     // rare threshold: |subj_j| < thr <=> |t| < EPS
    rp.w = 0.f;
    rowpack[row] = rp;
  }
}

// ---------------------------------------------------------------------------
// Outer kernel: ONE ROW PER BLOCK (1-D grid, 8192 blocks). Each block writes
// one fully contiguous 32 KB row; consecutive blocks = consecutive rows, so
// the aggregate store stream is linear like the 7 TB/s fill kernel (2-D
// column-window tilings all plateaued at ~5.9 TB/s). Column data m2/subj is
// re-read per chunk from L1/L2 (64 KB shared set, L2-resident). Fast path per
// element: sign-compare + cndmask(a*LPOS, a*LNEG) + mul. Rare |t|<EPS path
// exact; diag zeroed via unsigned-range check. tid*4 layout: each store
// instruction is a contiguous 1 KB/wave (tid*8 measured slower: 32 B-stride
// partial-line stores, 54.8 us). nt stores measured slower (62.9). Persistent
// grid measured slower (53.0, VGPR-occupancy).
// ---------------------------------------------------------------------------
__device__ __forceinline__ float exact_elem(float a, float oi, float m2c,
                                            float sjc) {
  const float t = oi * sjc;
  const float z = t / fmaxf(fabsf(t), EPS);
  return a * m2c * (1.f / (1.f + __expf(-z)));
}

__global__ __launch_bounds__(256) void outer_kernel(
    const float4* __restrict__ rowpack, const float* __restrict__ m2,
    const float* __restrict__ subj, float* __restrict__ out) {
  const int i = blockIdx.x;
  const float4 rp = rowpack[i];       // block-uniform -> scalar load
  const float a = rp.x, oi = rp.y, thr = rp.z;
  const float aLP = a * LPOS;
  const float aLN = a * LNEG;
  const bool neg = oi < 0.f;
  float* __restrict__ outrow = out + (size_t)i * N;
  const int t4 = threadIdx.x * 4;
#pragma unroll
  for (int c = 0; c < N / 1024; ++c) {
    const int j = c * 1024 + t4;
    const float4 m2v = *reinterpret_cast<const float4*>(m2 + j);
    const float4 sjv = *reinterpret_cast<const float4*>(subj + j);
    float4 o;
    o.x = m2v.x * (((sjv.x > 0.f) != neg) ? aLP : aLN);
    o.y = m2v.y * (((sjv.y > 0.f) != neg) ? aLP : aLN);
    o.z = m2v.z * (((sjv.z > 0.f) != neg) ? aLP : aLN);
    o.w = m2v.w * (((sjv.w > 0.f) != neg) ? aLP : aLN);
    const float mn = fminf(fminf(fabsf(sjv.x), fabsf(sjv.y)),
                           fminf(fabsf(sjv.z), fabsf(sjv.w)));
    if (__builtin_expect(__any(mn < thr), 0)) {
      if (fabsf(sjv.x) < thr) o.x = exact_elem(a, oi, m2v.x, sjv.x);
      if (fabsf(sjv.y) < thr) o.y = exact_elem(a, oi, m2v.y, sjv.y);
      if (fabsf(sjv.z) < thr) o.z = exact_elem(a, oi, m2v.z, sjv.z);
      if (fabsf(sjv.w) < thr) o.w = exact_elem(a, oi, m2v.w, sjv.w);
    }
    if (__builtin_expect((unsigned)(i - j) < 4u, 0)) {
      if (j + 0 == i) o.x = 0.f;
      if (j + 1 == i) o.y = 0.f;
      if (j + 2 == i) o.z = 0.f;
      if (j + 3 == i) o.w = 0.f;
    }
    *reinterpret_cast<float4*>(outrow + j) = o;
  }
}

// ---------------------------------------------------------------------------
extern "C" void kernel_launch(void* const* d_in, const int* in_sizes, int n_in,
                              void* d_out, int out_size, void* d_ws,
                              size_t ws_size, hipStream_t stream) {
  const float* pat1 = (const float*)d_in[0];
  const float* pat2 = (const float*)d_in[1];
  const float* wm   = (const float*)d_in[2];
  const float* Wp   = (const float*)d_in[3];
  const float* bp   = (const float*)d_in[4];
  const float* Wq   = (const float*)d_in[5];
  const float* bq   = (const float*)d_in[6];
  float* out = (float*)d_out;

  // ws layout: rowpack (N float4), m2 (N floats), subj (N floats)
  float4* rowpack = (float4*)d_ws;
  float* m2   = (float*)(rowpack + N);
  float* subj = m2 + N;

  match_kernel<<<N / 4, 256, 0, stream>>>(pat1, pat2, Wp, bp, wm, Wq, bq,
                                          rowpack, m2, subj);
  outer_kernel<<<N, 256, 0, stream>>>(rowpack, m2, subj, out);
}